// Round 1
// baseline (118.079 us; speedup 1.0000x reference)
//
#include <hip/hip_runtime.h>
#include <hip/hip_bf16.h>
#include <math.h>

// Problem constants (fixed by setup_inputs)
#define B_DOC 32
#define S_MAX 40
#define T_K 64
#define N_DIM 512
#define B_SENT (B_DOC * S_MAX)      // 1280
#define MAXDOC (S_MAX * T_K)        // 2560

__device__ __forceinline__ float fast_tanh(float x) {
    // tanh(x) = 1 - 2/(exp(2x)+1); exp via v_exp_f32. Handles +-inf saturate.
    float e = __expf(2.0f * x);
    return 1.0f - 2.0f * __builtin_amdgcn_rcpf(e + 1.0f);
}

// ---------------- prep: doc_ids / sent_local / doc_word_off / sent_start ----
__global__ __launch_bounds__(256) void prep_kernel(
        const int* __restrict__ seq_lens2, const int* __restrict__ sent_lens,
        int* __restrict__ doc_ids, int* __restrict__ sent_local,
        int* __restrict__ doc_word_off, int* __restrict__ sent_start_g) {
    __shared__ int ls[B_SENT];
    __shared__ int wc[B_SENT];
    __shared__ int ss[B_DOC + 1];
    __shared__ int csum[256];
    int tid = threadIdx.x;
    for (int i = tid; i < B_SENT; i += 256) ls[i] = seq_lens2[i];
    if (tid < B_DOC) ss[tid + 1] = sent_lens[tid];
    __syncthreads();
    // per-thread chunk sums (5 elems each)
    int base = tid * 5;
    int sum = 0;
    #pragma unroll
    for (int k = 0; k < 5; ++k) sum += ls[base + k];
    csum[tid] = sum;
    __syncthreads();
    if (tid == 0) {
        ss[0] = 0;
        for (int b = 0; b < B_DOC; ++b) ss[b + 1] += ss[b];
        int acc = 0;
        for (int i = 0; i < 256; ++i) { int v = csum[i]; csum[i] = acc; acc += v; }
    }
    __syncthreads();
    int acc = csum[tid];
    #pragma unroll
    for (int k = 0; k < 5; ++k) { wc[base + k] = acc; acc += ls[base + k]; }
    __syncthreads();
    for (int i = tid; i < B_SENT; i += 256) {
        int b = 0;
        while (b < B_DOC - 1 && ss[b + 1] <= i) ++b;
        doc_ids[i] = b;
        sent_local[i] = i - ss[b];
        doc_word_off[i] = wc[i] - wc[ss[b]];
    }
    if (tid < B_DOC + 1) sent_start_g[tid] = ss[tid];
}

// ---------------- dec_fea = x @ W + b (two 32x512 GEMV batches) -------------
__global__ __launch_bounds__(256) void fea_kernel(
        const float* __restrict__ s_t_hat, const float* __restrict__ sent_s_t_hat,
        const float* __restrict__ Wd, const float* __restrict__ bd,
        const float* __restrict__ Wsd, const float* __restrict__ bsd,
        float* __restrict__ dec_fea, float* __restrict__ sent_dec_fea) {
    int m = blockIdx.x >> 5;     // 0: word-level, 1: sentence-level
    int b = blockIdx.x & 31;
    const float* x = (m == 0 ? s_t_hat : sent_s_t_hat) + b * N_DIM;
    const float* W = (m == 0 ? Wd : Wsd);
    const float* bias = (m == 0 ? bd : bsd);
    float* out = (m == 0 ? dec_fea : sent_dec_fea) + b * N_DIM;
    __shared__ float xs[N_DIM];
    int tid = threadIdx.x;
    xs[tid] = x[tid];
    xs[tid + 256] = x[tid + 256];
    __syncthreads();
    float a0 = bias[tid], a1 = bias[tid + 256];
    #pragma unroll 4
    for (int k = 0; k < N_DIM; ++k) {
        float xv = xs[k];
        a0 = fmaf(xv, W[k * N_DIM + tid], a0);
        a1 = fmaf(xv, W[k * N_DIM + tid + 256], a1);
    }
    out[tid] = a0;
    out[tid + 256] = a1;
}

// ---------------- init: zero attn_dist_sw, copy coverage --------------------
__global__ __launch_bounds__(256) void init_kernel(
        const float* __restrict__ cov_in, float* __restrict__ out_attn,
        float* __restrict__ out_cov, int n) {
    int i = blockIdx.x * 256 + threadIdx.x;
    if (i < n) {
        out_attn[i] = 0.0f;
        out_cov[i] = cov_in[i];
    }
}

// ---------------- word-level attention (heavy: reads encoder_feature) -------
__global__ __launch_bounds__(256) void word_attn_kernel(
        const float* __restrict__ ef, const float* __restrict__ dec_fea,
        const float* __restrict__ v_w, const int* __restrict__ seq_lens2,
        const int* __restrict__ doc_ids, float* __restrict__ w_attn) {
    int s = blockIdx.x;
    __shared__ float df[N_DIM];
    __shared__ float vw[N_DIM];
    __shared__ float sc[T_K];
    int tid = threadIdx.x;
    int doc = doc_ids[s];
    for (int i = tid; i < N_DIM; i += 256) {
        df[i] = dec_fea[doc * N_DIM + i];
        vw[i] = v_w[i];
    }
    __syncthreads();
    int w = tid >> 6, lane = tid & 63;
    int len = seq_lens2[s];
    const float4* ef4 = (const float4*)(ef + (size_t)s * T_K * N_DIM);
    const float4* df4 = (const float4*)df;
    const float4* vw4 = (const float4*)vw;
    for (int t = w; t < len; t += 4) {          // skip invalid words entirely
        float acc = 0.0f;
        #pragma unroll
        for (int j = 0; j < 2; ++j) {
            int n4 = lane + 64 * j;
            float4 e = ef4[t * 128 + n4];
            float4 d = df4[n4];
            float4 v = vw4[n4];
            acc = fmaf(v.x, fast_tanh(e.x + d.x), acc);
            acc = fmaf(v.y, fast_tanh(e.y + d.y), acc);
            acc = fmaf(v.z, fast_tanh(e.z + d.z), acc);
            acc = fmaf(v.w, fast_tanh(e.w + d.w), acc);
        }
        #pragma unroll
        for (int off = 32; off >= 1; off >>= 1) acc += __shfl_xor(acc, off, 64);
        if (lane == 0) sc[t] = acc;
    }
    __syncthreads();
    if (tid < T_K) {
        bool valid = tid < len;
        float x = valid ? sc[tid] : -INFINITY;
        float m = x;
        #pragma unroll
        for (int off = 32; off >= 1; off >>= 1) m = fmaxf(m, __shfl_xor(m, off, 64));
        float e = valid ? __expf(x - m) : 0.0f;
        float ssum = e;
        #pragma unroll
        for (int off = 32; off >= 1; off >>= 1) ssum += __shfl_xor(ssum, off, 64);
        w_attn[s * T_K + tid] = e / ssum;
    }
}

// ---------------- sentence-level attention ----------------------------------
__global__ __launch_bounds__(256) void sent_attn_kernel(
        const float* __restrict__ sef, const float* __restrict__ sent_dec_fea,
        const float* __restrict__ sv_w, const float* __restrict__ mask,
        float* __restrict__ out_sent) {
    int b = blockIdx.x;
    __shared__ float df[N_DIM];
    __shared__ float vw[N_DIM];
    __shared__ float sc[S_MAX];
    int tid = threadIdx.x;
    for (int i = tid; i < N_DIM; i += 256) {
        df[i] = sent_dec_fea[b * N_DIM + i];
        vw[i] = sv_w[i];
    }
    __syncthreads();
    int w = tid >> 6, lane = tid & 63;
    const float4* sef4 = (const float4*)(sef + (size_t)b * S_MAX * N_DIM);
    const float4* df4 = (const float4*)df;
    const float4* vw4 = (const float4*)vw;
    for (int t = w; t < S_MAX; t += 4) {
        float acc = 0.0f;
        #pragma unroll
        for (int j = 0; j < 2; ++j) {
            int n4 = lane + 64 * j;
            float4 e = sef4[t * 128 + n4];
            float4 d = df4[n4];
            float4 v = vw4[n4];
            acc = fmaf(v.x, fast_tanh(e.x + d.x), acc);
            acc = fmaf(v.y, fast_tanh(e.y + d.y), acc);
            acc = fmaf(v.z, fast_tanh(e.z + d.z), acc);
            acc = fmaf(v.w, fast_tanh(e.w + d.w), acc);
        }
        #pragma unroll
        for (int off = 32; off >= 1; off >>= 1) acc += __shfl_xor(acc, off, 64);
        if (lane == 0) sc[t] = acc;
    }
    __syncthreads();
    if (tid < 64) {
        bool valid = tid < S_MAX;
        float x = valid ? sc[tid] : -INFINITY;
        float m = x;
        #pragma unroll
        for (int off = 32; off >= 1; off >>= 1) m = fmaxf(m, __shfl_xor(m, off, 64));
        float mk = valid ? mask[b * S_MAX + tid] : 0.0f;
        float e = valid ? __expf(x - m) * mk : 0.0f;
        float ssum = e;
        #pragma unroll
        for (int off = 32; off >= 1; off >>= 1) ssum += __shfl_xor(ssum, off, 64);
        if (valid) out_sent[b * S_MAX + tid] = e / ssum;
    }
}

// ---------------- per-sentence partial c_t + attn_dist_sw scatter -----------
__global__ __launch_bounds__(256) void part_kernel(
        const float* __restrict__ enc_out, const float* __restrict__ w_attn,
        const float* __restrict__ sent_attn, const int* __restrict__ doc_ids,
        const int* __restrict__ sent_local, const int* __restrict__ doc_word_off,
        const int* __restrict__ seq_lens2, const int* __restrict__ mdl,
        float* __restrict__ part, float* __restrict__ out_attn) {
    int s = blockIdx.x;
    int tid = threadIdx.x;
    __shared__ float mult[T_K];
    __shared__ float4 red[256];
    int doc = doc_ids[s];
    int len = seq_lens2[s];
    if (tid < T_K) {
        float sa = sent_attn[doc * S_MAX + sent_local[s]];
        float m = (tid < len) ? sa * w_attn[s * T_K + tid] : 0.0f;
        mult[tid] = m;
        if (tid < len) out_attn[(size_t)doc * mdl[0] + doc_word_off[s] + tid] = m;
    }
    __syncthreads();
    int nq = tid & 127;   // float4 column index (covers 512 floats)
    int tq = tid >> 7;    // 0/1 — word-dim split
    float4 acc = {0.f, 0.f, 0.f, 0.f};
    const float4* e4 = (const float4*)(enc_out + (size_t)s * T_K * N_DIM);
    for (int t = tq; t < len; t += 2) {         // skip invalid words (zero weight)
        float m = mult[t];
        float4 e = e4[t * 128 + nq];
        acc.x = fmaf(m, e.x, acc.x);
        acc.y = fmaf(m, e.y, acc.y);
        acc.z = fmaf(m, e.z, acc.z);
        acc.w = fmaf(m, e.w, acc.w);
    }
    red[tid] = acc;
    __syncthreads();
    if (tq == 0) {
        float4 a = red[nq];
        float4 o = red[nq + 128];
        float4 r = {a.x + o.x, a.y + o.y, a.z + o.z, a.w + o.w};
        ((float4*)(part + (size_t)s * N_DIM))[nq] = r;
    }
}

// ---------------- deterministic per-doc reduction: c_t ----------------------
__global__ __launch_bounds__(128) void reduce_kernel(
        const float* __restrict__ part, const int* __restrict__ sent_start,
        float* __restrict__ c_t) {
    int b = blockIdx.x;
    int nq = threadIdx.x;    // 128 float4 columns
    int st = sent_start[b], en = sent_start[b + 1];
    float4 acc = {0.f, 0.f, 0.f, 0.f};
    for (int s = st; s < en; ++s) {
        float4 p = ((const float4*)(part + (size_t)s * N_DIM))[nq];
        acc.x += p.x; acc.y += p.y; acc.z += p.z; acc.w += p.w;
    }
    ((float4*)(c_t + (size_t)b * N_DIM))[nq] = acc;
}

extern "C" void kernel_launch(void* const* d_in, const int* in_sizes, int n_in,
                              void* d_out, int out_size, void* d_ws, size_t ws_size,
                              hipStream_t stream) {
    const float* s_t_hat        = (const float*)d_in[0];
    const float* encoder_out    = (const float*)d_in[1];
    const float* encoder_feat   = (const float*)d_in[2];
    const int*   seq_lens2      = (const int*)d_in[3];
    const float* sent_s_t_hat   = (const float*)d_in[4];
    // d_in[5] sent_enc_outputs — unused by the reference computation
    const float* sent_enc_feat  = (const float*)d_in[6];
    const float* sent_pad_mask  = (const float*)d_in[7];
    const int*   sent_lens      = (const int*)d_in[8];
    const int*   max_doc_len    = (const int*)d_in[9];
    const float* coverage       = (const float*)d_in[10];
    const float* Wd             = (const float*)d_in[11];
    const float* bd             = (const float*)d_in[12];
    const float* v_w            = (const float*)d_in[13];
    const float* Wsd            = (const float*)d_in[14];
    const float* bsd            = (const float*)d_in[15];
    const float* sv_w           = (const float*)d_in[16];

    // output layout: c_t[32*512] | attn_dist_sw[32*2560] | coverage[1280*64] | sent_attn[32*40]
    float* out      = (float*)d_out;
    float* o_ct     = out;
    float* o_attn   = out + B_DOC * N_DIM;                          // 16384
    float* o_cov    = o_attn + B_DOC * MAXDOC;                      // +81920
    float* o_sent   = o_cov + B_SENT * T_K;                         // +81920

    // workspace layout (floats)
    float* ws          = (float*)d_ws;
    float* dec_fea     = ws;                                        // 16384
    float* sent_dec    = ws + 16384;                                // 16384
    float* w_attn      = ws + 32768;                                // 81920
    float* part        = ws + 114688;                               // 655360
    int*   ints        = (int*)(ws + 770048);
    int*   doc_ids     = ints;                                      // 1280
    int*   sent_local  = ints + B_SENT;                             // 1280
    int*   doc_w_off   = ints + 2 * B_SENT;                         // 1280
    int*   sent_start  = ints + 3 * B_SENT;                         // 33

    prep_kernel<<<1, 256, 0, stream>>>(seq_lens2, sent_lens, doc_ids, sent_local,
                                       doc_w_off, sent_start);
    fea_kernel<<<64, 256, 0, stream>>>(s_t_hat, sent_s_t_hat, Wd, bd, Wsd, bsd,
                                       dec_fea, sent_dec);
    init_kernel<<<(B_SENT * T_K + 255) / 256, 256, 0, stream>>>(coverage, o_attn,
                                                                o_cov, B_SENT * T_K);
    word_attn_kernel<<<B_SENT, 256, 0, stream>>>(encoder_feat, dec_fea, v_w,
                                                 seq_lens2, doc_ids, w_attn);
    sent_attn_kernel<<<B_DOC, 256, 0, stream>>>(sent_enc_feat, sent_dec, sv_w,
                                                sent_pad_mask, o_sent);
    part_kernel<<<B_SENT, 256, 0, stream>>>(encoder_out, w_attn, o_sent, doc_ids,
                                            sent_local, doc_w_off, seq_lens2,
                                            max_doc_len, part, o_attn);
    reduce_kernel<<<B_DOC, 128, 0, stream>>>(part, sent_start, o_ct);
}

// Round 2
// 80.514 us; speedup vs baseline: 1.4666x; 1.4666x over previous
//
#include <hip/hip_runtime.h>
#include <hip/hip_bf16.h>
#include <math.h>

// Problem constants (fixed by setup_inputs)
#define B_DOC 32
#define S_MAX 40
#define T_K 64
#define N_DIM 512
#define B_SENT (B_DOC * S_MAX)      // 1280
#define MAXDOC (S_MAX * T_K)        // 2560
#define KCHUNK 4                    // fea GEMV k-split

__device__ __forceinline__ float fast_tanh(float x) {
    float e = __expf(2.0f * x);
    return 1.0f - 2.0f * __builtin_amdgcn_rcpf(e + 1.0f);
}

// ---------------- prep: fully parallel scans --------------------------------
// outputs: doc_ids[1280], sent_local[1280], doc_word_off[1280],
//          sent_start[33], doc_words_total[32]
__global__ __launch_bounds__(256) void prep_kernel(
        const int* __restrict__ seq_lens2, const int* __restrict__ sent_lens,
        int* __restrict__ doc_ids, int* __restrict__ sent_local,
        int* __restrict__ doc_word_off, int* __restrict__ sent_start_g,
        int* __restrict__ doc_words_total) {
    __shared__ int ss[B_DOC + 1];
    __shared__ int wc[B_SENT + 1];
    __shared__ int wsum[4];
    int tid = threadIdx.x;
    int lane = tid & 63, w = tid >> 6;

    // each thread loads 5 word-lengths
    int ls[5];
    #pragma unroll
    for (int k = 0; k < 5; ++k) ls[k] = seq_lens2[tid * 5 + k];
    int sum = ls[0] + ls[1] + ls[2] + ls[3] + ls[4];

    // wave-level inclusive scan of per-thread sums
    int scan = sum;
    #pragma unroll
    for (int off = 1; off < 64; off <<= 1) {
        int v = __shfl_up(scan, off, 64);
        if (lane >= off) scan += v;
    }
    if (lane == 63) wsum[w] = scan;

    // wave 0: sent_lens scan -> ss (sentence start per doc)
    if (w == 0) {
        int sl = (lane < B_DOC) ? sent_lens[lane] : 0;
        int sc2 = sl;
        #pragma unroll
        for (int off = 1; off < 64; off <<= 1) {
            int v = __shfl_up(sc2, off, 64);
            if (lane >= off) sc2 += v;
        }
        if (lane < B_DOC) ss[lane + 1] = sc2;
        if (lane == 0) ss[0] = 0;
    }
    __syncthreads();

    // cross-wave offset (w < 4, trivial)
    int wbase = 0;
    for (int i = 0; i < w; ++i) wbase += wsum[i];
    int excl = wbase + scan - sum;
    #pragma unroll
    for (int k = 0; k < 5; ++k) { wc[tid * 5 + k] = excl; excl += ls[k]; }
    if (tid == 255) wc[B_SENT] = excl;
    __syncthreads();

    if (tid <= B_DOC) sent_start_g[tid] = ss[tid];
    if (tid < B_DOC) doc_words_total[tid] = wc[ss[tid + 1]] - wc[ss[tid]];

    for (int i = tid; i < B_SENT; i += 256) {
        // binary search: largest b with ss[b] <= i
        int lo = 0, hi = B_DOC - 1;
        while (lo < hi) { int mid = (lo + hi + 1) >> 1; if (ss[mid] <= i) lo = mid; else hi = mid - 1; }
        doc_ids[i] = lo;
        sent_local[i] = i - ss[lo];
        doc_word_off[i] = wc[i] - wc[ss[lo]];
    }
}

// ---------------- dec_fea partials: k-split GEMV ----------------------------
// grid = 2 mats * 32 docs * KCHUNK; block computes partial over 128 k-values
// fea_part layout: [(m*32+b)*KCHUNK + c][512]
__global__ __launch_bounds__(256) void fea_kernel(
        const float* __restrict__ s_t_hat, const float* __restrict__ sent_s_t_hat,
        const float* __restrict__ Wd, const float* __restrict__ bd,
        const float* __restrict__ Wsd, const float* __restrict__ bsd,
        float* __restrict__ fea_part) {
    int blk = blockIdx.x;
    int c = blk & (KCHUNK - 1);
    int b = (blk >> 2) & 31;
    int m = blk >> 7;
    const int KC = N_DIM / KCHUNK;   // 128
    const float* x = (m ? sent_s_t_hat : s_t_hat) + b * N_DIM + c * KC;
    const float* W = (m ? Wsd : Wd) + (size_t)c * KC * N_DIM;
    const float* bias = (m ? bsd : bd);
    float* out = fea_part + ((size_t)(m * 32 + b) * KCHUNK + c) * N_DIM;
    __shared__ float xs[128];
    int tid = threadIdx.x;
    if (tid < KC) xs[tid] = x[tid];
    __syncthreads();
    float a0 = 0.f, a1 = 0.f;
    if (c == 0) { a0 = bias[tid]; a1 = bias[tid + 256]; }
    #pragma unroll 8
    for (int k = 0; k < KC; ++k) {
        float xv = xs[k];
        a0 = fmaf(xv, W[k * N_DIM + tid], a0);
        a1 = fmaf(xv, W[k * N_DIM + tid + 256], a1);
    }
    out[tid] = a0;
    out[tid + 256] = a1;
}

// ---------------- sentence-level attention ----------------------------------
__global__ __launch_bounds__(256) void sent_attn_kernel(
        const float* __restrict__ sef, const float* __restrict__ fea_part,
        const float* __restrict__ sv_w, const float* __restrict__ mask,
        float* __restrict__ out_sent) {
    int b = blockIdx.x;
    __shared__ float df[N_DIM];
    __shared__ float vw[N_DIM];
    __shared__ float sc[S_MAX];
    int tid = threadIdx.x;
    const float* fp = fea_part + (size_t)(32 + b) * KCHUNK * N_DIM;
    for (int i = tid; i < N_DIM; i += 256) {
        df[i] = fp[i] + fp[N_DIM + i] + fp[2 * N_DIM + i] + fp[3 * N_DIM + i];
        vw[i] = sv_w[i];
    }
    __syncthreads();
    int w = tid >> 6, lane = tid & 63;
    const float4* sef4 = (const float4*)(sef + (size_t)b * S_MAX * N_DIM);
    const float4* df4 = (const float4*)df;
    const float4* vw4 = (const float4*)vw;
    for (int t = w; t < S_MAX; t += 4) {
        float acc = 0.0f;
        #pragma unroll
        for (int j = 0; j < 2; ++j) {
            int n4 = lane + 64 * j;
            float4 e = sef4[t * 128 + n4];
            float4 d = df4[n4];
            float4 v = vw4[n4];
            acc = fmaf(v.x, fast_tanh(e.x + d.x), acc);
            acc = fmaf(v.y, fast_tanh(e.y + d.y), acc);
            acc = fmaf(v.z, fast_tanh(e.z + d.z), acc);
            acc = fmaf(v.w, fast_tanh(e.w + d.w), acc);
        }
        #pragma unroll
        for (int off = 32; off >= 1; off >>= 1) acc += __shfl_xor(acc, off, 64);
        if (lane == 0) sc[t] = acc;
    }
    __syncthreads();
    if (tid < 64) {
        bool valid = tid < S_MAX;
        float x = valid ? sc[tid] : -INFINITY;
        float m = x;
        #pragma unroll
        for (int off = 32; off >= 1; off >>= 1) m = fmaxf(m, __shfl_xor(m, off, 64));
        float mk = valid ? mask[b * S_MAX + tid] : 0.0f;
        float e = valid ? __expf(x - m) * mk : 0.0f;
        float ssum = e;
        #pragma unroll
        for (int off = 32; off >= 1; off >>= 1) ssum += __shfl_xor(ssum, off, 64);
        if (valid) out_sent[b * S_MAX + tid] = e / ssum;
    }
}

// ---------------- fused: word attention + mult + context partial ------------
// Per sentence s: scores+softmax (reads encoder_feature), mult_attn write
// (attn_dist_sw), weighted context partial (reads encoder_outputs),
// coverage copy, tail zeroing for last sentence of each doc.
__global__ __launch_bounds__(256) void fused_kernel(
        const float* __restrict__ ef, const float* __restrict__ eo,
        const float* __restrict__ fea_part, const float* __restrict__ v_w,
        const float* __restrict__ sent_attn, const int* __restrict__ seq_lens2,
        const int* __restrict__ doc_ids, const int* __restrict__ sent_local,
        const int* __restrict__ doc_word_off, const int* __restrict__ sent_start,
        const int* __restrict__ doc_words_total, const int* __restrict__ mdl,
        const float* __restrict__ cov_in,
        float* __restrict__ part, float* __restrict__ out_attn,
        float* __restrict__ out_cov) {
    int s = blockIdx.x;
    int tid = threadIdx.x;
    __shared__ float df[N_DIM];
    __shared__ float vw[N_DIM];
    __shared__ float sc[T_K];
    __shared__ float mult[T_K];
    __shared__ float4 red[256];

    int doc = doc_ids[s];
    int len = seq_lens2[s];
    int maxdoc = mdl[0];

    const float* fp = fea_part + (size_t)doc * KCHUNK * N_DIM;
    for (int i = tid; i < N_DIM; i += 256) {
        df[i] = fp[i] + fp[N_DIM + i] + fp[2 * N_DIM + i] + fp[3 * N_DIM + i];
        vw[i] = v_w[i];
    }
    // coverage passthrough (1280 blocks x 64 = full array)
    if (tid < T_K) out_cov[s * T_K + tid] = cov_in[s * T_K + tid];
    __syncthreads();

    // ---- phase A: scores + softmax (valid words only) ----
    int w = tid >> 6, lane = tid & 63;
    const float4* ef4 = (const float4*)(ef + (size_t)s * T_K * N_DIM);
    const float4* df4 = (const float4*)df;
    const float4* vw4 = (const float4*)vw;
    for (int t = w; t < len; t += 4) {
        float acc = 0.0f;
        #pragma unroll
        for (int j = 0; j < 2; ++j) {
            int n4 = lane + 64 * j;
            float4 e = ef4[t * 128 + n4];
            float4 d = df4[n4];
            float4 v = vw4[n4];
            acc = fmaf(v.x, fast_tanh(e.x + d.x), acc);
            acc = fmaf(v.y, fast_tanh(e.y + d.y), acc);
            acc = fmaf(v.z, fast_tanh(e.z + d.z), acc);
            acc = fmaf(v.w, fast_tanh(e.w + d.w), acc);
        }
        #pragma unroll
        for (int off = 32; off >= 1; off >>= 1) acc += __shfl_xor(acc, off, 64);
        if (lane == 0) sc[t] = acc;
    }
    __syncthreads();
    if (tid < T_K) {
        bool valid = tid < len;
        float x = valid ? sc[tid] : -INFINITY;
        float m = x;
        #pragma unroll
        for (int off = 32; off >= 1; off >>= 1) m = fmaxf(m, __shfl_xor(m, off, 64));
        float e = valid ? __expf(x - m) : 0.0f;
        float ssum = e;
        #pragma unroll
        for (int off = 32; off >= 1; off >>= 1) ssum += __shfl_xor(ssum, off, 64);
        float sa = sent_attn[doc * S_MAX + sent_local[s]];
        float mu = valid ? sa * (e / ssum) : 0.0f;
        mult[tid] = mu;
        if (valid) out_attn[(size_t)doc * maxdoc + doc_word_off[s] + tid] = mu;
    }
    // tail zeroing: last sentence of each doc zeroes [doc_words, maxdoc)
    if (s + 1 == sent_start[doc + 1]) {
        int dwt = doc_words_total[doc];
        for (int i = dwt + tid; i < maxdoc; i += 256)
            out_attn[(size_t)doc * maxdoc + i] = 0.0f;
    }
    __syncthreads();

    // ---- phase B: weighted context partial ----
    int nq = tid & 127;   // float4 column (512 floats)
    int tq = tid >> 7;    // word-dim split
    float4 acc = {0.f, 0.f, 0.f, 0.f};
    const float4* e4 = (const float4*)(eo + (size_t)s * T_K * N_DIM);
    for (int t = tq; t < len; t += 2) {
        float m = mult[t];
        float4 e = e4[t * 128 + nq];
        acc.x = fmaf(m, e.x, acc.x);
        acc.y = fmaf(m, e.y, acc.y);
        acc.z = fmaf(m, e.z, acc.z);
        acc.w = fmaf(m, e.w, acc.w);
    }
    red[tid] = acc;
    __syncthreads();
    if (tq == 0) {
        float4 a = red[nq];
        float4 o = red[nq + 128];
        float4 r = {a.x + o.x, a.y + o.y, a.z + o.z, a.w + o.w};
        ((float4*)(part + (size_t)s * N_DIM))[nq] = r;
    }
}

// ---------------- deterministic per-doc reduction: c_t ----------------------
__global__ __launch_bounds__(128) void reduce_kernel(
        const float* __restrict__ part, const int* __restrict__ sent_start,
        float* __restrict__ c_t) {
    int b = blockIdx.x;
    int nq = threadIdx.x;    // 128 float4 columns
    int st = sent_start[b], en = sent_start[b + 1];
    float4 acc = {0.f, 0.f, 0.f, 0.f};
    for (int s = st; s < en; ++s) {
        float4 p = ((const float4*)(part + (size_t)s * N_DIM))[nq];
        acc.x += p.x; acc.y += p.y; acc.z += p.z; acc.w += p.w;
    }
    ((float4*)(c_t + (size_t)b * N_DIM))[nq] = acc;
}

extern "C" void kernel_launch(void* const* d_in, const int* in_sizes, int n_in,
                              void* d_out, int out_size, void* d_ws, size_t ws_size,
                              hipStream_t stream) {
    const float* s_t_hat        = (const float*)d_in[0];
    const float* encoder_out    = (const float*)d_in[1];
    const float* encoder_feat   = (const float*)d_in[2];
    const int*   seq_lens2      = (const int*)d_in[3];
    const float* sent_s_t_hat   = (const float*)d_in[4];
    // d_in[5] sent_enc_outputs — unused by the reference computation
    const float* sent_enc_feat  = (const float*)d_in[6];
    const float* sent_pad_mask  = (const float*)d_in[7];
    const int*   sent_lens      = (const int*)d_in[8];
    const int*   max_doc_len    = (const int*)d_in[9];
    const float* coverage       = (const float*)d_in[10];
    const float* Wd             = (const float*)d_in[11];
    const float* bd             = (const float*)d_in[12];
    const float* v_w            = (const float*)d_in[13];
    const float* Wsd            = (const float*)d_in[14];
    const float* bsd            = (const float*)d_in[15];
    const float* sv_w           = (const float*)d_in[16];

    // output layout: c_t[32*512] | attn_dist_sw[32*2560] | coverage[1280*64] | sent_attn[32*40]
    float* out      = (float*)d_out;
    float* o_ct     = out;
    float* o_attn   = out + B_DOC * N_DIM;
    float* o_cov    = o_attn + B_DOC * MAXDOC;
    float* o_sent   = o_cov + B_SENT * T_K;

    // workspace layout (floats)
    float* ws          = (float*)d_ws;
    float* fea_part    = ws;                                   // 2*32*4*512 = 131072
    float* part        = ws + 131072;                          // 1280*512 = 655360
    int*   ints        = (int*)(ws + 131072 + 655360);
    int*   doc_ids     = ints;                                 // 1280
    int*   sent_local  = ints + B_SENT;                        // 1280
    int*   doc_w_off   = ints + 2 * B_SENT;                    // 1280
    int*   sent_start  = ints + 3 * B_SENT;                    // 33
    int*   doc_wtot    = ints + 3 * B_SENT + 33;               // 32

    prep_kernel<<<1, 256, 0, stream>>>(seq_lens2, sent_lens, doc_ids, sent_local,
                                       doc_w_off, sent_start, doc_wtot);
    fea_kernel<<<2 * 32 * KCHUNK, 256, 0, stream>>>(s_t_hat, sent_s_t_hat, Wd, bd,
                                                    Wsd, bsd, fea_part);
    sent_attn_kernel<<<B_DOC, 256, 0, stream>>>(sent_enc_feat, fea_part, sv_w,
                                                sent_pad_mask, o_sent);
    fused_kernel<<<B_SENT, 256, 0, stream>>>(encoder_feat, encoder_out, fea_part,
                                             v_w, o_sent, seq_lens2, doc_ids,
                                             sent_local, doc_w_off, sent_start,
                                             doc_wtot, max_doc_len, coverage,
                                             part, o_attn, o_cov);
    reduce_kernel<<<B_DOC, 128, 0, stream>>>(part, sent_start, o_ct);
}